// Round 11
// baseline (35.449 us; speedup 1.0000x reference)
//
#include <hip/hip_runtime.h>
#include <math.h>

#define Bsz 8
#define NP 9
#define OC 8
#define TILE 256           // pixels per block (2 image rows)
#define BPB 64             // blocks per batch
#define THREADS 256
#define NR 72              // (cls,pt) pairs

// Kernel 1 (byte-identical to round 10): per-block class-gather reduction.
// Round 11 probe: launched 4x to disjoint regions; k2 reads the 4th.
// k1 = (dur - 14.36us)/3.
__global__ __launch_bounds__(THREADS) void cls_vote_partial(
    const float* __restrict__ seg, const float* __restrict__ direct,
    const float* __restrict__ wts, float* __restrict__ partial)
{
    __shared__ float ls_dir[TILE * 18];         // 18432 B
    __shared__ float ls_w[TILE * 9];            //  9216 B
    __shared__ float ls_seg[TILE * 9];          //  9216 B (reused as merge)
    __shared__ unsigned char ls_list[OC * TILE];//  2048 B
    __shared__ int ls_cnt[4][OC];               //   128 B
    __shared__ int ls_off[4][OC];               //   128 B
    __shared__ int ls_total[OC];                //    32 B  (~39.2 KB -> 4 blk/CU)
    float (*ls_merge)[5] = (float(*)[5])ls_seg; // alias: seg dead after phase A

    const int b = blockIdx.y;
    const int tid = threadIdx.x;
    const int lane = tid & 63;
    const int w = tid >> 6;
    const long gbase = (long)b * 16384 + blockIdx.x * TILE;

    // ---- coalesced float4 staging of seg/dir/w ----
    {
        const float4* gs = (const float4*)(seg + gbase * 9);     // 576 float4
        const float4* gd = (const float4*)(direct + gbase * 18); // 1152 float4
        const float4* gw = (const float4*)(wts + gbase * 9);     // 576 float4
        float4* s4 = (float4*)ls_seg;
        float4* d4 = (float4*)ls_dir;
        float4* w4 = (float4*)ls_w;
#pragma unroll
        for (int k = 0; k < 2; ++k) s4[tid + k * THREADS] = gs[tid + k * THREADS];
        if (tid < 64) s4[tid + 512] = gs[tid + 512];
#pragma unroll
        for (int k = 0; k < 4; ++k) d4[tid + k * THREADS] = gd[tid + k * THREADS];
        if (tid < 128) d4[tid + 1024] = gd[tid + 1024];
#pragma unroll
        for (int k = 0; k < 2; ++k) w4[tid + k * THREADS] = gw[tid + k * THREADS];
        if (tid < 64) w4[tid + 512] = gw[tid + 512];
    }
    __syncthreads();

    // ---- Phase A: argmax from LDS + ballot compaction ----
    int cls;
    int mypos = 0;
    {
        const float* s = ls_seg + tid * 9;
        float m = s[0];
        int am = 0;
#pragma unroll
        for (int c = 1; c < 9; ++c) {
            float v = s[c];
            if (v > m) { m = v; am = c; }
        }
        cls = am - 1;  // -1 = background

        const unsigned long long lt = (1ull << lane) - 1ull;
#pragma unroll
        for (int c = 0; c < OC; ++c) {
            unsigned long long mask = __ballot(cls == c);
            if (lane == 0) ls_cnt[w][c] = __popcll(mask);
            if (cls == c) mypos = __popcll(mask & lt);
        }
    }
    __syncthreads();

    if (tid < OC) {  // cross-wave exclusive prefix per class
        int base = 0;
#pragma unroll
        for (int ww = 0; ww < 4; ++ww) {
            ls_off[ww][tid] = base;
            base += ls_cnt[ww][tid];
        }
        ls_total[tid] = base;
    }
    __syncthreads();

    if (cls >= 0)
        ls_list[cls * TILE + ls_off[w][cls] + mypos] = (unsigned char)tid;
    __syncthreads();

    // ---- Phase B: gather over compacted lists, accumulate in registers ----
    if (tid < 216) {
        const int s  = tid % 3;
        const int pp = (tid / 3) % 9;
        const int cl = tid / 27;
        const int n = ls_total[cl];
        const unsigned char* list = ls_list + cl * TILE;
        const float rowbase = (float)(blockIdx.x * 2) + 0.5f;

        float a0 = 0.f, a1 = 0.f, a2 = 0.f, a3 = 0.f, a4 = 0.f;
        for (int k = s; k < n; k += 3) {
            const int pix = list[k];
            const float2 nd = *(const float2*)(ls_dir + pix * 18 + pp * 2);
            const float wx = ls_w[pix * 9 + pp];
            float e = __expf(wx);
            float sp = (wx > 15.f) ? wx : __logf(1.f + e);
            float nx = nd.x, ny = nd.y;
            float nn = nx * nx + ny * ny;
            float R00, R01, R11;
            if (nn > 0.f) {
                float inv = __builtin_amdgcn_rcpf(nn);
                R00 = sp * (1.f - nx * nx * inv);
                R01 = -sp * (nx * ny * inv);
                R11 = sp * (1.f - ny * ny * inv);
            } else {  // divide_no_nan: n == 0 -> R = w * I
                R00 = sp; R01 = 0.f; R11 = sp;
            }
            float ch = (rowbase + (float)(pix >> 7)) * 0.0078125f;
            float cw = ((float)(pix & 127) + 0.5f) * 0.0078125f;
            a0 += R00;
            a1 += R01;
            a2 += R11;
            a3 += R00 * ch + R01 * cw;
            a4 += R01 * ch + R11 * cw;
        }
        ls_merge[tid][0] = a0;
        ls_merge[tid][1] = a1;
        ls_merge[tid][2] = a2;
        ls_merge[tid][3] = a3;
        ls_merge[tid][4] = a4;
    }
    __syncthreads();

    // ---- merge 3 slices, write transposed block partial ----
    if (tid < NR) {
        float* outp = partial + ((long)(b * NR + tid) * BPB + blockIdx.x) * 5;
#pragma unroll
        for (int f = 0; f < 5; ++f)
            outp[f] = ls_merge[tid * 3 + 0][f] + ls_merge[tid * 3 + 1][f] +
                      ls_merge[tid * 3 + 2][f];
    }
}

// Kernel 2: one wave per (b,cls,pt). 64 lanes read 64 consecutive 20-B
// records (coalesced 1280 B), f64 butterfly reduce, lane 0 solves 2x2.
__global__ __launch_bounds__(256) void cls_vote_solve(
    const float* __restrict__ partial, float* __restrict__ out)
{
    const int wave = threadIdx.x >> 6;
    const int lane = threadIdx.x & 63;
    const int id = blockIdx.x * 4 + wave;   // (b*72 + r), r = cls*9+pt
    if (id >= Bsz * NR) return;

    const float* pp = partial + ((long)id * BPB + lane) * 5;
    double a  = (double)pp[0];
    double bb = (double)pp[1];
    double c  = (double)pp[2];
    double q0 = (double)pp[3];
    double q1 = (double)pp[4];

#pragma unroll
    for (int off = 1; off < 64; off <<= 1) {
        a  += __shfl_xor(a, off, 64);
        bb += __shfl_xor(bb, off, 64);
        c  += __shfl_xor(c, off, 64);
        q0 += __shfl_xor(q0, off, 64);
        q1 += __shfl_xor(q1, off, 64);
    }

    if (lane == 0) {
        double det = a * c - bb * bb;
        double p0 = 0.0, p1 = 0.0;
        if (det != 0.0) {
            double ia = c / det, ib = -bb / det, ic = a / det;
            p0 = ia * q0 + ib * q1;
            p1 = ib * q0 + ic * q1;
        }
        out[2 * id + 0] = (float)(p0 * 128.0);
        out[2 * id + 1] = (float)(p1 * 128.0);
    }
}

extern "C" void kernel_launch(void* const* d_in, const int* in_sizes, int n_in,
                              void* d_out, int out_size, void* d_ws, size_t ws_size,
                              hipStream_t stream) {
    const float* seg    = (const float*)d_in[0];
    const float* direct = (const float*)d_in[1];
    const float* wts    = (const float*)d_in[2];
    float* out = (float*)d_out;
    float* pA = (float*)d_ws;                // 4 disjoint 737,280-B regions
    float* pB = (float*)d_ws + 184320;
    float* pC = (float*)d_ws + 368640;
    float* pD = (float*)d_ws + 552960;

    dim3 grid1(BPB, Bsz);
    // Differential probe: 3 extra k1 instances; k1 = (dur - 14.36us)/3.
    cls_vote_partial<<<grid1, THREADS, 0, stream>>>(seg, direct, wts, pA);
    cls_vote_partial<<<grid1, THREADS, 0, stream>>>(seg, direct, wts, pB);
    cls_vote_partial<<<grid1, THREADS, 0, stream>>>(seg, direct, wts, pC);
    cls_vote_partial<<<grid1, THREADS, 0, stream>>>(seg, direct, wts, pD);

    int nwaves = Bsz * NR;          // 576 waves, 4 per block
    cls_vote_solve<<<nwaves / 4, 256, 0, stream>>>(pD, out);
}

// Round 12
// 17.452 us; speedup vs baseline: 2.0313x; 2.0313x over previous
//
#include <hip/hip_runtime.h>
#include <math.h>

#define Bsz 8
#define NP 9
#define OC 8
#define TILE 256           // pixels per block (2 image rows)
#define BPB 64             // blocks per batch
#define THREADS 256
#define NR 72              // (cls,pt) pairs
#define FLAG_MAGIC 0x1357BDFu

// Single fused kernel, fence-free fan-in.
// Phase A: seg staged via float4 -> LDS, argmax, ballot compaction.
// Phase B: 216 threads walk class lists, accumulate R/q in registers.
// Phase C: partials published via RELAXED agent-scope (sc1/LLC) atomic
//          stores -- no __threadfence, no L2 writeback. __syncthreads'
//          implicit vmcnt(0) orders them before the relaxed flag store.
//          Blocks 0..8 of each batch reduce 8 rows each (4 waves x 2) with
//          relaxed atomic loads (LLC truth, immune to stale local L2).
__global__ __launch_bounds__(THREADS) void cls_vote_fused(
    const float* __restrict__ seg, const float* __restrict__ direct,
    const float* __restrict__ wts, float* __restrict__ partial,
    unsigned* __restrict__ flags, float* __restrict__ out)
{
    __shared__ float ls_dir[TILE * 18];         // 18432 B
    __shared__ float ls_w[TILE * 9];            //  9216 B
    __shared__ float ls_seg[TILE * 9];          //  9216 B (reused as merge)
    __shared__ unsigned char ls_list[OC * TILE];//  2048 B
    __shared__ int ls_cnt[4][OC];               //   128 B
    __shared__ int ls_off[4][OC];               //   128 B
    __shared__ int ls_total[OC];                //    32 B  (~39.2 KB -> 4 blk/CU)
    float (*ls_merge)[5] = (float(*)[5])ls_seg; // alias: seg dead after phase A

    const int b = blockIdx.y;
    const int tid = threadIdx.x;
    const int lane = tid & 63;
    const int w = tid >> 6;
    const long gbase = (long)b * 16384 + blockIdx.x * TILE;

    // ---- coalesced float4 staging of seg/dir/w ----
    {
        const float4* gs = (const float4*)(seg + gbase * 9);     // 576 float4
        const float4* gd = (const float4*)(direct + gbase * 18); // 1152 float4
        const float4* gw = (const float4*)(wts + gbase * 9);     // 576 float4
        float4* s4 = (float4*)ls_seg;
        float4* d4 = (float4*)ls_dir;
        float4* w4 = (float4*)ls_w;
#pragma unroll
        for (int k = 0; k < 2; ++k) s4[tid + k * THREADS] = gs[tid + k * THREADS];
        if (tid < 64) s4[tid + 512] = gs[tid + 512];
#pragma unroll
        for (int k = 0; k < 4; ++k) d4[tid + k * THREADS] = gd[tid + k * THREADS];
        if (tid < 128) d4[tid + 1024] = gd[tid + 1024];
#pragma unroll
        for (int k = 0; k < 2; ++k) w4[tid + k * THREADS] = gw[tid + k * THREADS];
        if (tid < 64) w4[tid + 512] = gw[tid + 512];
    }
    __syncthreads();

    // ---- Phase A: argmax from LDS + ballot compaction ----
    int cls;
    int mypos = 0;
    {
        const float* s = ls_seg + tid * 9;
        float m = s[0];
        int am = 0;
#pragma unroll
        for (int c = 1; c < 9; ++c) {
            float v = s[c];
            if (v > m) { m = v; am = c; }
        }
        cls = am - 1;  // -1 = background

        const unsigned long long lt = (1ull << lane) - 1ull;
#pragma unroll
        for (int c = 0; c < OC; ++c) {
            unsigned long long mask = __ballot(cls == c);
            if (lane == 0) ls_cnt[w][c] = __popcll(mask);
            if (cls == c) mypos = __popcll(mask & lt);
        }
    }
    __syncthreads();

    if (tid < OC) {  // cross-wave exclusive prefix per class
        int base = 0;
#pragma unroll
        for (int ww = 0; ww < 4; ++ww) {
            ls_off[ww][tid] = base;
            base += ls_cnt[ww][tid];
        }
        ls_total[tid] = base;
    }
    __syncthreads();

    if (cls >= 0)
        ls_list[cls * TILE + ls_off[w][cls] + mypos] = (unsigned char)tid;
    __syncthreads();

    // ---- Phase B: gather over compacted lists, accumulate in registers ----
    if (tid < 216) {
        const int s  = tid % 3;
        const int pp = (tid / 3) % 9;
        const int cl = tid / 27;
        const int n = ls_total[cl];
        const unsigned char* list = ls_list + cl * TILE;
        const float rowbase = (float)(blockIdx.x * 2) + 0.5f;

        float a0 = 0.f, a1 = 0.f, a2 = 0.f, a3 = 0.f, a4 = 0.f;
        for (int k = s; k < n; k += 3) {
            const int pix = list[k];
            const float2 nd = *(const float2*)(ls_dir + pix * 18 + pp * 2);
            const float wx = ls_w[pix * 9 + pp];
            float e = __expf(wx);
            float sp = (wx > 15.f) ? wx : __logf(1.f + e);
            float nx = nd.x, ny = nd.y;
            float nn = nx * nx + ny * ny;
            float R00, R01, R11;
            if (nn > 0.f) {
                float inv = __builtin_amdgcn_rcpf(nn);
                R00 = sp * (1.f - nx * nx * inv);
                R01 = -sp * (nx * ny * inv);
                R11 = sp * (1.f - ny * ny * inv);
            } else {  // divide_no_nan: n == 0 -> R = w * I
                R00 = sp; R01 = 0.f; R11 = sp;
            }
            float ch = (rowbase + (float)(pix >> 7)) * 0.0078125f;
            float cw = ((float)(pix & 127) + 0.5f) * 0.0078125f;
            a0 += R00;
            a1 += R01;
            a2 += R11;
            a3 += R00 * ch + R01 * cw;
            a4 += R01 * ch + R11 * cw;
        }
        ls_merge[tid][0] = a0;
        ls_merge[tid][1] = a1;
        ls_merge[tid][2] = a2;
        ls_merge[tid][3] = a3;
        ls_merge[tid][4] = a4;
    }
    __syncthreads();

    // ---- Phase C: publish partial via relaxed LLC stores ----
    if (tid < NR) {
        float* outp = partial + ((long)(b * NR + tid) * BPB + blockIdx.x) * 5;
#pragma unroll
        for (int f = 0; f < 5; ++f) {
            float v = ls_merge[tid * 3 + 0][f] + ls_merge[tid * 3 + 1][f] +
                      ls_merge[tid * 3 + 2][f];
            __hip_atomic_store(&outp[f], v, __ATOMIC_RELAXED,
                               __HIP_MEMORY_SCOPE_AGENT);
        }
    }
    __syncthreads();  // implicit vmcnt(0): partial stores acked at LLC

    if (tid == 0)
        __hip_atomic_store(&flags[b * BPB + blockIdx.x], FLAG_MAGIC,
                           __ATOMIC_RELAXED, __HIP_MEMORY_SCOPE_AGENT);

    if (blockIdx.x >= 9) return;

    // ---- reducer: wait for this batch's 64 flags (relaxed polls, no inv) ----
    if (tid < BPB) {
        for (;;) {
            unsigned v = __hip_atomic_load(&flags[b * BPB + tid],
                                           __ATOMIC_RELAXED,
                                           __HIP_MEMORY_SCOPE_AGENT);
            if (__all(v == FLAG_MAGIC)) break;
            __builtin_amdgcn_s_sleep(4);
        }
    }
    __syncthreads();
    __builtin_amdgcn_sched_barrier(0);

    // 8 rows per reducer block: wave w handles rows blockIdx.x*8 + w*2 + {0,1}
#pragma unroll
    for (int rr = 0; rr < 2; ++rr) {
        const int r = blockIdx.x * 8 + w * 2 + rr;
        const float* pp = partial + ((long)(b * NR + r) * BPB + lane) * 5;
        double a  = (double)__hip_atomic_load(&pp[0], __ATOMIC_RELAXED,
                                              __HIP_MEMORY_SCOPE_AGENT);
        double bb = (double)__hip_atomic_load(&pp[1], __ATOMIC_RELAXED,
                                              __HIP_MEMORY_SCOPE_AGENT);
        double c  = (double)__hip_atomic_load(&pp[2], __ATOMIC_RELAXED,
                                              __HIP_MEMORY_SCOPE_AGENT);
        double q0 = (double)__hip_atomic_load(&pp[3], __ATOMIC_RELAXED,
                                              __HIP_MEMORY_SCOPE_AGENT);
        double q1 = (double)__hip_atomic_load(&pp[4], __ATOMIC_RELAXED,
                                              __HIP_MEMORY_SCOPE_AGENT);

#pragma unroll
        for (int off = 1; off < 64; off <<= 1) {
            a  += __shfl_xor(a, off, 64);
            bb += __shfl_xor(bb, off, 64);
            c  += __shfl_xor(c, off, 64);
            q0 += __shfl_xor(q0, off, 64);
            q1 += __shfl_xor(q1, off, 64);
        }

        if (lane == 0) {
            double det = a * c - bb * bb;
            double p0 = 0.0, p1 = 0.0;
            if (det != 0.0) {
                double ia = c / det, ib = -bb / det, ic = a / det;
                p0 = ia * q0 + ib * q1;
                p1 = ib * q0 + ic * q1;
            }
            const int id = b * NR + r;
            out[2 * id + 0] = (float)(p0 * 128.0);
            out[2 * id + 1] = (float)(p1 * 128.0);
        }
    }
}

extern "C" void kernel_launch(void* const* d_in, const int* in_sizes, int n_in,
                              void* d_out, int out_size, void* d_ws, size_t ws_size,
                              hipStream_t stream) {
    const float* seg    = (const float*)d_in[0];
    const float* direct = (const float*)d_in[1];
    const float* wts    = (const float*)d_in[2];
    float* out = (float*)d_out;
    float* partial = (float*)d_ws;                       // 737,280 B
    unsigned* flags = (unsigned*)((char*)d_ws + 737280); // 2,048 B

    dim3 grid(BPB, Bsz);
    cls_vote_fused<<<grid, THREADS, 0, stream>>>(seg, direct, wts, partial,
                                                 flags, out);
}

// Round 13
// 15.780 us; speedup vs baseline: 2.2464x; 1.1059x over previous
//
#include <hip/hip_runtime.h>
#include <math.h>

#define Bsz 8
#define NP 9
#define OC 8
#define TILE 128           // pixels per block = ONE image row
#define BPB 128            // blocks per batch
#define THREADS 256
#define NR 72              // (cls,pt) pairs

// Kernel 1: per-block class-gather reduction, zero atomics.
// TILE=128 -> 1024 blocks (4/CU, 16 waves/CU) to hide per-block latency.
// Phase A: seg staged via float4 -> LDS, argmax (2 waves), ballot compaction.
// Phase B: 216 threads = (8 cls x 9 pts x 3 slices) walk their class list,
//          recompute softplus/R/q from staged dir/w, accumulate in registers.
// Partial layout transposed for k2: [(b*72 + r)*128 + blk]*5 + f.
__global__ __launch_bounds__(THREADS) void cls_vote_partial(
    const float* __restrict__ seg, const float* __restrict__ direct,
    const float* __restrict__ wts, float* __restrict__ partial)
{
    __shared__ float ls_dir[TILE * 18];         // 9216 B
    __shared__ float ls_w[TILE * 9];            // 4608 B
    __shared__ float ls_seg[TILE * 9];          // 4608 B (reused as merge)
    __shared__ unsigned char ls_list[OC * TILE];// 1024 B
    __shared__ int ls_cnt[2][OC];               //   64 B
    __shared__ int ls_off[2][OC];               //   64 B
    __shared__ int ls_total[OC];                //   32 B   (~19.7 KB -> 8 blk/CU cap)
    float (*ls_merge)[5] = (float(*)[5])ls_seg; // alias: seg dead after phase A

    const int b = blockIdx.y;
    const int tid = threadIdx.x;
    const int lane = tid & 63;
    const int w = tid >> 6;
    const long gbase = (long)b * 16384 + blockIdx.x * TILE;

    // ---- coalesced float4 staging of seg/dir/w ----
    {
        const float4* gs = (const float4*)(seg + gbase * 9);     // 288 float4
        const float4* gd = (const float4*)(direct + gbase * 18); // 576 float4
        const float4* gw = (const float4*)(wts + gbase * 9);     // 288 float4
        float4* s4 = (float4*)ls_seg;
        float4* d4 = (float4*)ls_dir;
        float4* w4 = (float4*)ls_w;
        s4[tid] = gs[tid];
        if (tid < 32) s4[tid + 256] = gs[tid + 256];             // 256..287
#pragma unroll
        for (int k = 0; k < 2; ++k) d4[tid + k * THREADS] = gd[tid + k * THREADS];
        if (tid < 64) d4[tid + 512] = gd[tid + 512];             // 512..575
        w4[tid % 256] = gw[tid % 256];  // plain: tid<256 always true
        if (tid < 32) w4[tid + 256] = gw[tid + 256];             // 256..287
    }
    __syncthreads();

    // ---- Phase A: argmax from LDS + ballot compaction (pixels = tid<128) ----
    int cls = -1;
    int mypos = 0;
    if (tid < TILE) {
        const float* s = ls_seg + tid * 9;
        float m = s[0];
        int am = 0;
#pragma unroll
        for (int c = 1; c < 9; ++c) {
            float v = s[c];
            if (v > m) { m = v; am = c; }
        }
        cls = am - 1;  // -1 = background

        const unsigned long long lt = (1ull << lane) - 1ull;
#pragma unroll
        for (int c = 0; c < OC; ++c) {
            unsigned long long mask = __ballot(cls == c);
            if (lane == 0) ls_cnt[w][c] = __popcll(mask);
            if (cls == c) mypos = __popcll(mask & lt);
        }
    }
    __syncthreads();

    if (tid < OC) {  // exclusive prefix over the 2 pixel-waves
        int base = 0;
#pragma unroll
        for (int ww = 0; ww < 2; ++ww) {
            ls_off[ww][tid] = base;
            base += ls_cnt[ww][tid];
        }
        ls_total[tid] = base;
    }
    __syncthreads();

    if (cls >= 0)
        ls_list[cls * TILE + ls_off[w][cls] + mypos] = (unsigned char)tid;
    __syncthreads();

    // ---- Phase B: gather over compacted lists, accumulate in registers ----
    if (tid < 216) {
        const int s  = tid % 3;
        const int pp = (tid / 3) % 9;
        const int cl = tid / 27;
        const int n = ls_total[cl];
        const unsigned char* list = ls_list + cl * TILE;
        const float ch = ((float)blockIdx.x + 0.5f) * 0.0078125f; // row coord

        float a0 = 0.f, a1 = 0.f, a2 = 0.f, a3 = 0.f, a4 = 0.f;
        for (int k = s; k < n; k += 3) {
            const int pix = list[k];
            const float2 nd = *(const float2*)(ls_dir + pix * 18 + pp * 2);
            const float wx = ls_w[pix * 9 + pp];
            float e = __expf(wx);
            float sp = (wx > 15.f) ? wx : __logf(1.f + e);
            float nx = nd.x, ny = nd.y;
            float nn = nx * nx + ny * ny;
            float R00, R01, R11;
            if (nn > 0.f) {
                float inv = __builtin_amdgcn_rcpf(nn);
                R00 = sp * (1.f - nx * nx * inv);
                R01 = -sp * (nx * ny * inv);
                R11 = sp * (1.f - ny * ny * inv);
            } else {  // divide_no_nan: n == 0 -> R = w * I
                R00 = sp; R01 = 0.f; R11 = sp;
            }
            float cw = ((float)pix + 0.5f) * 0.0078125f;          // col coord
            a0 += R00;
            a1 += R01;
            a2 += R11;
            a3 += R00 * ch + R01 * cw;
            a4 += R01 * ch + R11 * cw;
        }
        ls_merge[tid][0] = a0;
        ls_merge[tid][1] = a1;
        ls_merge[tid][2] = a2;
        ls_merge[tid][3] = a3;
        ls_merge[tid][4] = a4;
    }
    __syncthreads();

    // ---- merge 3 slices, write transposed block partial ----
    if (tid < NR) {
        float* outp = partial + ((long)(b * NR + tid) * BPB + blockIdx.x) * 5;
#pragma unroll
        for (int f = 0; f < 5; ++f)
            outp[f] = ls_merge[tid * 3 + 0][f] + ls_merge[tid * 3 + 1][f] +
                      ls_merge[tid * 3 + 2][f];
    }
}

// Kernel 2: one wave per (b,cls,pt). 64 lanes read 2x64 consecutive 20-B
// records (coalesced), f64 add + butterfly reduce, lane 0 solves 2x2.
__global__ __launch_bounds__(256) void cls_vote_solve(
    const float* __restrict__ partial, float* __restrict__ out)
{
    const int wave = threadIdx.x >> 6;
    const int lane = threadIdx.x & 63;
    const int id = blockIdx.x * 4 + wave;   // (b*72 + r), r = cls*9+pt
    if (id >= Bsz * NR) return;

    const float* p0 = partial + ((long)id * BPB + lane) * 5;
    const float* p1 = partial + ((long)id * BPB + 64 + lane) * 5;
    double a  = (double)p0[0] + (double)p1[0];
    double bb = (double)p0[1] + (double)p1[1];
    double c  = (double)p0[2] + (double)p1[2];
    double q0 = (double)p0[3] + (double)p1[3];
    double q1 = (double)p0[4] + (double)p1[4];

#pragma unroll
    for (int off = 1; off < 64; off <<= 1) {
        a  += __shfl_xor(a, off, 64);
        bb += __shfl_xor(bb, off, 64);
        c  += __shfl_xor(c, off, 64);
        q0 += __shfl_xor(q0, off, 64);
        q1 += __shfl_xor(q1, off, 64);
    }

    if (lane == 0) {
        double det = a * c - bb * bb;
        double r0 = 0.0, r1 = 0.0;
        if (det != 0.0) {
            double ia = c / det, ib = -bb / det, ic = a / det;
            r0 = ia * q0 + ib * q1;
            r1 = ib * q0 + ic * q1;
        }
        out[2 * id + 0] = (float)(r0 * 128.0);
        out[2 * id + 1] = (float)(r1 * 128.0);
    }
}

extern "C" void kernel_launch(void* const* d_in, const int* in_sizes, int n_in,
                              void* d_out, int out_size, void* d_ws, size_t ws_size,
                              hipStream_t stream) {
    const float* seg    = (const float*)d_in[0];
    const float* direct = (const float*)d_in[1];
    const float* wts    = (const float*)d_in[2];
    float* out = (float*)d_out;
    float* partial = (float*)d_ws;  // 8*72*128*5*4 = 1,474,560 B

    dim3 grid1(BPB, Bsz);
    cls_vote_partial<<<grid1, THREADS, 0, stream>>>(seg, direct, wts, partial);

    int nwaves = Bsz * NR;          // 576 waves, 4 per block
    cls_vote_solve<<<nwaves / 4, 256, 0, stream>>>(partial, out);
}

// Round 14
// 14.535 us; speedup vs baseline: 2.4388x; 1.0857x over previous
//
#include <hip/hip_runtime.h>
#include <math.h>

#define Bsz 8
#define NP 9
#define OC 8
#define TILE 128           // pixels per block = ONE image row
#define BPB 128            // blocks per batch
#define THREADS 256
#define NR 72              // (cls,pt) pairs

// Kernel 1: per-block class-gather reduction, zero atomics.
// TILE=128 -> 1024 blocks (4/CU, 16 waves/CU) to hide per-block latency.
// Phase A: seg staged via float4 -> LDS, argmax (2 waves), ballot compaction.
// Phase B: 216 threads = (8 cls x 9 pts x 3 slices) walk their class list,
//          recompute softplus/R/q from staged dir/w, accumulate in registers.
// Partial layout transposed for k2: [(b*72 + r)*128 + blk]*5 + f.
__global__ __launch_bounds__(THREADS) void cls_vote_partial(
    const float* __restrict__ seg, const float* __restrict__ direct,
    const float* __restrict__ wts, float* __restrict__ partial)
{
    __shared__ float ls_dir[TILE * 18];         // 9216 B
    __shared__ float ls_w[TILE * 9];            // 4608 B
    __shared__ float ls_seg[TILE * 9];          // 4608 B (reused as merge)
    __shared__ unsigned char ls_list[OC * TILE];// 1024 B
    __shared__ int ls_cnt[2][OC];               //   64 B
    __shared__ int ls_off[2][OC];               //   64 B
    __shared__ int ls_total[OC];                //   32 B   (~19.7 KB -> 8 blk/CU cap)
    float (*ls_merge)[5] = (float(*)[5])ls_seg; // alias: seg dead after phase A

    const int b = blockIdx.y;
    const int tid = threadIdx.x;
    const int lane = tid & 63;
    const int w = tid >> 6;
    const long gbase = (long)b * 16384 + blockIdx.x * TILE;

    // ---- coalesced float4 staging of seg/dir/w ----
    {
        const float4* gs = (const float4*)(seg + gbase * 9);     // 288 float4
        const float4* gd = (const float4*)(direct + gbase * 18); // 576 float4
        const float4* gw = (const float4*)(wts + gbase * 9);     // 288 float4
        float4* s4 = (float4*)ls_seg;
        float4* d4 = (float4*)ls_dir;
        float4* w4 = (float4*)ls_w;
        s4[tid] = gs[tid];
        if (tid < 32) s4[tid + 256] = gs[tid + 256];             // 256..287
#pragma unroll
        for (int k = 0; k < 2; ++k) d4[tid + k * THREADS] = gd[tid + k * THREADS];
        if (tid < 64) d4[tid + 512] = gd[tid + 512];             // 512..575
        w4[tid % 256] = gw[tid % 256];  // plain: tid<256 always true
        if (tid < 32) w4[tid + 256] = gw[tid + 256];             // 256..287
    }
    __syncthreads();

    // ---- Phase A: argmax from LDS + ballot compaction (pixels = tid<128) ----
    int cls = -1;
    int mypos = 0;
    if (tid < TILE) {
        const float* s = ls_seg + tid * 9;
        float m = s[0];
        int am = 0;
#pragma unroll
        for (int c = 1; c < 9; ++c) {
            float v = s[c];
            if (v > m) { m = v; am = c; }
        }
        cls = am - 1;  // -1 = background

        const unsigned long long lt = (1ull << lane) - 1ull;
#pragma unroll
        for (int c = 0; c < OC; ++c) {
            unsigned long long mask = __ballot(cls == c);
            if (lane == 0) ls_cnt[w][c] = __popcll(mask);
            if (cls == c) mypos = __popcll(mask & lt);
        }
    }
    __syncthreads();

    if (tid < OC) {  // exclusive prefix over the 2 pixel-waves
        int base = 0;
#pragma unroll
        for (int ww = 0; ww < 2; ++ww) {
            ls_off[ww][tid] = base;
            base += ls_cnt[ww][tid];
        }
        ls_total[tid] = base;
    }
    __syncthreads();

    if (cls >= 0)
        ls_list[cls * TILE + ls_off[w][cls] + mypos] = (unsigned char)tid;
    __syncthreads();

    // ---- Phase B: gather over compacted lists, accumulate in registers ----
    if (tid < 216) {
        const int s  = tid % 3;
        const int pp = (tid / 3) % 9;
        const int cl = tid / 27;
        const int n = ls_total[cl];
        const unsigned char* list = ls_list + cl * TILE;
        const float ch = ((float)blockIdx.x + 0.5f) * 0.0078125f; // row coord

        float a0 = 0.f, a1 = 0.f, a2 = 0.f, a3 = 0.f, a4 = 0.f;
        for (int k = s; k < n; k += 3) {
            const int pix = list[k];
            const float2 nd = *(const float2*)(ls_dir + pix * 18 + pp * 2);
            const float wx = ls_w[pix * 9 + pp];
            float e = __expf(wx);
            float sp = (wx > 15.f) ? wx : __logf(1.f + e);
            float nx = nd.x, ny = nd.y;
            float nn = nx * nx + ny * ny;
            float R00, R01, R11;
            if (nn > 0.f) {
                float inv = __builtin_amdgcn_rcpf(nn);
                R00 = sp * (1.f - nx * nx * inv);
                R01 = -sp * (nx * ny * inv);
                R11 = sp * (1.f - ny * ny * inv);
            } else {  // divide_no_nan: n == 0 -> R = w * I
                R00 = sp; R01 = 0.f; R11 = sp;
            }
            float cw = ((float)pix + 0.5f) * 0.0078125f;          // col coord
            a0 += R00;
            a1 += R01;
            a2 += R11;
            a3 += R00 * ch + R01 * cw;
            a4 += R01 * ch + R11 * cw;
        }
        ls_merge[tid][0] = a0;
        ls_merge[tid][1] = a1;
        ls_merge[tid][2] = a2;
        ls_merge[tid][3] = a3;
        ls_merge[tid][4] = a4;
    }
    __syncthreads();

    // ---- merge 3 slices, write transposed block partial ----
    if (tid < NR) {
        float* outp = partial + ((long)(b * NR + tid) * BPB + blockIdx.x) * 5;
#pragma unroll
        for (int f = 0; f < 5; ++f)
            outp[f] = ls_merge[tid * 3 + 0][f] + ls_merge[tid * 3 + 1][f] +
                      ls_merge[tid * 3 + 2][f];
    }
}

// Kernel 2: one wave per (b,cls,pt). 64 lanes read 2x64 consecutive 20-B
// records (coalesced), f64 add + butterfly reduce, lane 0 solves 2x2.
__global__ __launch_bounds__(256) void cls_vote_solve(
    const float* __restrict__ partial, float* __restrict__ out)
{
    const int wave = threadIdx.x >> 6;
    const int lane = threadIdx.x & 63;
    const int id = blockIdx.x * 4 + wave;   // (b*72 + r), r = cls*9+pt
    if (id >= Bsz * NR) return;

    const float* p0 = partial + ((long)id * BPB + lane) * 5;
    const float* p1 = partial + ((long)id * BPB + 64 + lane) * 5;
    double a  = (double)p0[0] + (double)p1[0];
    double bb = (double)p0[1] + (double)p1[1];
    double c  = (double)p0[2] + (double)p1[2];
    double q0 = (double)p0[3] + (double)p1[3];
    double q1 = (double)p0[4] + (double)p1[4];

#pragma unroll
    for (int off = 1; off < 64; off <<= 1) {
        a  += __shfl_xor(a, off, 64);
        bb += __shfl_xor(bb, off, 64);
        c  += __shfl_xor(c, off, 64);
        q0 += __shfl_xor(q0, off, 64);
        q1 += __shfl_xor(q1, off, 64);
    }

    if (lane == 0) {
        double det = a * c - bb * bb;
        double r0 = 0.0, r1 = 0.0;
        if (det != 0.0) {
            double ia = c / det, ib = -bb / det, ic = a / det;
            r0 = ia * q0 + ib * q1;
            r1 = ib * q0 + ic * q1;
        }
        out[2 * id + 0] = (float)(r0 * 128.0);
        out[2 * id + 1] = (float)(r1 * 128.0);
    }
}

extern "C" void kernel_launch(void* const* d_in, const int* in_sizes, int n_in,
                              void* d_out, int out_size, void* d_ws, size_t ws_size,
                              hipStream_t stream) {
    const float* seg    = (const float*)d_in[0];
    const float* direct = (const float*)d_in[1];
    const float* wts    = (const float*)d_in[2];
    float* out = (float*)d_out;
    float* partial = (float*)d_ws;  // 8*72*128*5*4 = 1,474,560 B

    dim3 grid1(BPB, Bsz);
    cls_vote_partial<<<grid1, THREADS, 0, stream>>>(seg, direct, wts, partial);

    int nwaves = Bsz * NR;          // 576 waves, 4 per block
    cls_vote_solve<<<nwaves / 4, 256, 0, stream>>>(partial, out);
}